// Round 3
// baseline (1769.514 us; speedup 1.0000x reference)
//
#include <hip/hip_runtime.h>

#define BB 4
#define N0 256
#define N1 256
#define NVOX 65536
#define NSUB 8
#define NLOR 32768
#define RAYLEN 256
#define CH 16
#define NXCD 8

// Transpose osem (B, NVOX) planar -> xt (NVOX, 4) so ray gathers are one float4.
__global__ __launch_bounds__(256) void k_transpose(const float* __restrict__ osem,
                                                   float* __restrict__ xt) {
    int v = blockIdx.x * blockDim.x + threadIdx.x;
    if (v >= NVOX) return;
    float4 o;
    o.x = osem[0 * NVOX + v];
    o.y = osem[1 * NVOX + v];
    o.z = osem[2 * NVOX + v];
    o.w = osem[3 * NVOX + v];
    ((float4*)xt)[v] = o;
}

// Fused fidelity: forward projection + ratio + backprojection, one wave per LOR.
// Backprojection scatters into a PER-XCD partial buffer with L2-local atomics
// (raw global_atomic_add_f32, no sc bits -> RMW executes in the local XCD L2,
// 8 parallel atomic pools instead of the ~20Gtxn/s memory-side pipe).
__global__ __launch_bounds__(256) void k_fid(
    const int* __restrict__ ridx,     // ray_idx + s*NLOR*RAYLEN
    const float* __restrict__ pw,     // proj_weights + s*NLOR*RAYLEN
    const float* __restrict__ xt,     // (NVOX,4)
    const float* __restrict__ data,   // data + s*NLOR ; index b*NSUB*NLOR + l
    const float* __restrict__ mult,   // same indexing
    const float* __restrict__ contam, // same indexing
    const float* __restrict__ norm,   // (B)
    float* __restrict__ part)         // (NXCD, NVOX, 4) partial backprojections
{
    const int wave = threadIdx.x >> 6;
    const int lane = threadIdx.x & 63;
    const int l = blockIdx.x * 4 + wave;
    const long base = (long)l * RAYLEN;

    unsigned xcc;
    asm("s_getreg_b32 %0, hwreg(HW_REG_XCC_ID)" : "=s"(xcc));
    float* mypart = part + (size_t)(xcc & (NXCD - 1)) * (NVOX * 4);

    int   idx[4];
    float wt[4];
    float ax = 0.f, ay = 0.f, az = 0.f, aw = 0.f;
#pragma unroll
    for (int k = 0; k < 4; ++k) {
        int r = lane + (k << 6);
        idx[k] = ridx[base + r];
        wt[k]  = pw[base + r];
        float4 xv = ((const float4*)xt)[idx[k]];
        ax += xv.x * wt[k];
        ay += xv.y * wt[k];
        az += xv.z * wt[k];
        aw += xv.w * wt[k];
    }
    // butterfly reduce across the 64-lane wave; all lanes end with the sums
#pragma unroll
    for (int off = 32; off >= 1; off >>= 1) {
        ax += __shfl_xor(ax, off);
        ay += __shfl_xor(ay, off);
        az += __shfl_xor(az, off);
        aw += __shfl_xor(aw, off);
    }
    float fwd[4] = {ax, ay, az, aw};
    float ratio[4];
#pragma unroll
    for (int b = 0; b < 4; ++b) {
        long o = (long)b * (NSUB * NLOR) + l;
        float m = mult[o];
        float e = m * (norm[b] * fwd[b]) + contam[o];
        ratio[b] = m * (1.0f - data[o] / e);
    }

    // lane L -> batch (L&3), point group (L>>2); 16 iterations cover 256 points.
    const int b = lane & 3;
    const float rb = (b == 0) ? ratio[0] : (b == 1) ? ratio[1] : (b == 2) ? ratio[2] : ratio[3];
    const int plane = lane >> 2;
#pragma unroll
    for (int k2 = 0; k2 < 16; ++k2) {
        const int reg = k2 >> 2;                         // compile-time after unroll
        const int src_lane = ((k2 & 3) << 4) | plane;    // holder of point p = plane + 16*k2
        int   ii = __shfl(idx[reg], src_lane);
        float ww = __shfl(wt[reg],  src_lane);
        float* p = mypart + (size_t)ii * 4 + b;
        float  val = ww * rb;
        // L2-local atomic: no sc0/sc1 -> stays in this XCD's L2 (mypart is XCD-private)
        asm volatile("global_atomic_add_f32 %0, %1, off" :: "v"(p), "v"(val) : "memory");
    }
}

// conv1: 1->16ch 3x3 SAME + bias + relu. Input from xt (NVOX,4), output h (B,NVOX,16).
__global__ __launch_bounds__(256) void k_conv1(
    const float* __restrict__ xt,
    const float* __restrict__ w1,  // (16,1,3,3)
    const float* __restrict__ b1,  // (16)
    float* __restrict__ h)         // (B, NVOX, 16)
{
    int t = blockIdx.x * blockDim.x + threadIdx.x;  // over B*NVOX
    int b = t >> 16;
    int v = t & 65535;
    int i = v >> 8, j = v & 255;
    float in[3][3];
#pragma unroll
    for (int di = 0; di < 3; ++di)
#pragma unroll
        for (int dj = 0; dj < 3; ++dj) {
            int ii = i + di - 1, jj = j + dj - 1;
            in[di][dj] = (ii >= 0 && ii < N0 && jj >= 0 && jj < N1)
                             ? xt[(size_t)((ii << 8) | jj) * 4 + b]
                             : 0.0f;
        }
    float* hp = h + (size_t)t * CH;
#pragma unroll
    for (int c = 0; c < CH; ++c) {
        float acc = b1[c];
#pragma unroll
        for (int di = 0; di < 3; ++di)
#pragma unroll
            for (int dj = 0; dj < 3; ++dj)
                acc += in[di][dj] * w1[c * 9 + di * 3 + dj];
        hp[c] = fmaxf(acc, 0.0f);
    }
}

// conv2 (16->1 3x3 SAME) fused with the MLEM combine:
// x_new = relu(osem - back*x/adj + nw * (conv2(h)+b2))
// Sums the 8 per-XCD partial backprojections and re-zeroes them for next iter.
__global__ __launch_bounds__(256) void k_combine(
    const float* __restrict__ h,      // (B,NVOX,16)
    const float* __restrict__ w2,     // (1,16,3,3)
    const float* __restrict__ b2,     // (1)
    float* __restrict__ part,         // (NXCD,NVOX,4)
    const float* __restrict__ xt_in,  // (NVOX,4)
    const float* __restrict__ osem,   // (B,NVOX)
    const float* __restrict__ adj,    // adjoint_ones + s*NVOX ; index b*NSUB*NVOX+v
    const float* __restrict__ nwp,    // scalar
    float* __restrict__ xt_out,       // (NVOX,4)
    float* __restrict__ out_planar)   // (B,NVOX) or nullptr
{
    int t = blockIdx.x * blockDim.x + threadIdx.x;  // over B*NVOX
    int b = t >> 16;
    int v = t & 65535;
    int i = v >> 8, j = v & 255;

    float o = b2[0];
#pragma unroll
    for (int di = 0; di < 3; ++di) {
        int ii = i + di - 1;
        if (ii < 0 || ii >= N0) continue;
#pragma unroll
        for (int dj = 0; dj < 3; ++dj) {
            int jj = j + dj - 1;
            if (jj < 0 || jj >= N1) continue;
            const float* hp = h + ((size_t)b * NVOX + ((ii << 8) | jj)) * CH;
#pragma unroll
            for (int c = 0; c < CH; ++c)
                o += hp[c] * w2[c * 9 + di * 3 + dj];
        }
    }
    // sum the 8 per-XCD partials; re-zero for the next iteration
    float bk = 0.0f;
#pragma unroll
    for (int p = 0; p < NXCD; ++p) {
        size_t off = (size_t)p * (NVOX * 4) + (size_t)v * 4 + b;
        bk += part[off];
        part[off] = 0.0f;
    }
    float xv = xt_in[(size_t)v * 4 + b];
    float x_data = bk * xv / adj[(size_t)b * NSUB * NVOX + v];
    float xnew = osem[t] - x_data + nwp[0] * o;
    xnew = fmaxf(xnew, 0.0f);
    xt_out[(size_t)v * 4 + b] = xnew;
    if (out_planar) out_planar[t] = xnew;
}

extern "C" void kernel_launch(void* const* d_in, const int* in_sizes, int n_in,
                              void* d_out, int out_size, void* d_ws, size_t ws_size,
                              hipStream_t stream) {
    const float* osem   = (const float*)d_in[0];
    const float* data   = (const float*)d_in[1];
    const float* mult   = (const float*)d_in[2];
    const float* contam = (const float*)d_in[3];
    const float* adj    = (const float*)d_in[4];
    const float* norm   = (const float*)d_in[5];
    const int*   ray_idx = (const int*)d_in[6];
    const float* pw     = (const float*)d_in[7];
    const float* w1     = (const float*)d_in[8];
    const float* b1     = (const float*)d_in[9];
    const float* w2     = (const float*)d_in[10];
    const float* b2     = (const float*)d_in[11];
    const float* nw     = (const float*)d_in[12];
    float* out = (float*)d_out;

    float* ws   = (float*)d_ws;
    float* xtA  = ws;                         // NVOX*4 floats (1MB)
    float* xtB  = ws + (size_t)NVOX * 4;      // 1MB
    float* part = ws + (size_t)NVOX * 8;      // NXCD*NVOX*4 floats (8MB)
    float* h    = ws + (size_t)NVOX * (8 + 4 * NXCD);  // B*NVOX*CH floats (16MB)

    k_transpose<<<NVOX / 256, 256, 0, stream>>>(osem, xtA);
    // zero the per-XCD partials (first call sees 0xAA poison; later iterations
    // are re-zeroed inside k_combine, and the last combine leaves them zeroed)
    hipMemsetAsync(part, 0, (size_t)NXCD * NVOX * 4 * sizeof(float), stream);

    const int subsets[4] = {0, 2, 4, 6};
    float* xin = xtA;
    float* xout = xtB;
    for (int it = 0; it < 4; ++it) {
        int s = subsets[it];
        k_fid<<<NLOR / 4, 256, 0, stream>>>(
            ray_idx + (size_t)s * NLOR * RAYLEN,
            pw + (size_t)s * NLOR * RAYLEN,
            xin,
            data + (size_t)s * NLOR,
            mult + (size_t)s * NLOR,
            contam + (size_t)s * NLOR,
            norm, part);
        k_conv1<<<(BB * NVOX) / 256, 256, 0, stream>>>(xin, w1, b1, h);
        k_combine<<<(BB * NVOX) / 256, 256, 0, stream>>>(
            h, w2, b2, part, xin, osem,
            adj + (size_t)s * NVOX, nw,
            xout, (it == 3) ? out : nullptr);
        float* tmp = xin; xin = xout; xout = tmp;
    }
}

// Round 4
// 1035.784 us; speedup vs baseline: 1.7084x; 1.7084x over previous
//
#include <hip/hip_runtime.h>

#define BB 4
#define N0 256
#define N1 256
#define NVOX 65536
#define NSUB 8
#define NLOR 32768
#define RAYLEN 256
#define CH 16
#define NPTS (NLOR * RAYLEN)
#define VOXT 32768   // voxels per LDS tile (1 batch plane, 128KB)

// Transpose osem (B, NVOX) planar -> xt (NVOX, 4) so ray gathers are one float4.
__global__ __launch_bounds__(256) void k_transpose(const float* __restrict__ osem,
                                                   float* __restrict__ xt) {
    int v = blockIdx.x * blockDim.x + threadIdx.x;
    if (v >= NVOX) return;
    float4 o;
    o.x = osem[0 * NVOX + v];
    o.y = osem[1 * NVOX + v];
    o.z = osem[2 * NVOX + v];
    o.w = osem[3 * NVOX + v];
    ((float4*)xt)[v] = o;
}

// Forward projection + ratio per LOR. One wave per LOR; writes ratio (NLOR,4).
__global__ __launch_bounds__(256) void k_fwd(
    const int* __restrict__ ridx,     // ray_idx + s*NPTS
    const float* __restrict__ pw,     // proj_weights + s*NPTS
    const float* __restrict__ xt,     // (NVOX,4)
    const float* __restrict__ data,   // + index b*NSUB*NLOR + l
    const float* __restrict__ mult,
    const float* __restrict__ contam,
    const float* __restrict__ norm,   // (B)
    float* __restrict__ ratio)        // (NLOR,4)
{
    const int wave = threadIdx.x >> 6;
    const int lane = threadIdx.x & 63;
    const int l = blockIdx.x * 4 + wave;
    const long base = (long)l * RAYLEN;

    float ax = 0.f, ay = 0.f, az = 0.f, aw = 0.f;
#pragma unroll
    for (int k = 0; k < 4; ++k) {
        int r = lane + (k << 6);
        float wt = pw[base + r];
        float4 xv = ((const float4*)xt)[ridx[base + r]];
        ax += xv.x * wt;
        ay += xv.y * wt;
        az += xv.z * wt;
        aw += xv.w * wt;
    }
#pragma unroll
    for (int off = 32; off >= 1; off >>= 1) {
        ax += __shfl_xor(ax, off);
        ay += __shfl_xor(ay, off);
        az += __shfl_xor(az, off);
        aw += __shfl_xor(aw, off);
    }
    if (lane == 0) {
        float fwd[4] = {ax, ay, az, aw};
        float rr[4];
#pragma unroll
        for (int b = 0; b < 4; ++b) {
            long o = (long)b * (NSUB * NLOR) + l;
            float m = mult[o];
            float e = m * (norm[b] * fwd[b]) + contam[o];
            rr[b] = m * (1.0f - data[o] / e);
        }
        ((float4*)ratio)[l] = make_float4(rr[0], rr[1], rr[2], rr[3]);
    }
}

// Atomic-free backprojection: block (chunk c, group g) accumulates batch (g&3),
// voxel half (g>>2) of its ray chunk into a 128KB LDS plane via ds_add_f32,
// then flushes with plain coalesced float4 stores into part[c][b][NVOX half].
__global__ __launch_bounds__(1024) void k_back(
    const int* __restrict__ ridx,     // ray_idx + s*NPTS
    const float* __restrict__ pw,     // proj_weights + s*NPTS
    const float* __restrict__ ratio,  // (NLOR,4)
    float* __restrict__ part,         // (C,4,NVOX)
    int PC)                           // points per chunk (multiple of 4096)
{
    __shared__ float acc[VOXT];
    const int c = blockIdx.x;
    const int g = blockIdx.y;         // 0..7
    const int b = g & 3;
    const int lo = (g >> 2) * VOXT;

    for (int q = threadIdx.x; q < VOXT; q += 1024) acc[q] = 0.0f;
    __syncthreads();

    const int pbeg = c * PC;
    const int pend = min(pbeg + PC, NPTS);
#pragma unroll 2
    for (int p = pbeg + (int)threadIdx.x * 4; p < pend; p += 1024 * 4) {
        int4   id = *(const int4*)(ridx + p);
        float4 w  = *(const float4*)(pw + p);
        float  r  = ratio[(p >> 8) * 4 + b];   // wave-uniform (one LOR per wave)
        unsigned r0 = (unsigned)(id.x - lo);
        unsigned r1 = (unsigned)(id.y - lo);
        unsigned r2 = (unsigned)(id.z - lo);
        unsigned r3 = (unsigned)(id.w - lo);
        if (r0 < VOXT) atomicAdd(&acc[r0], w.x * r);
        if (r1 < VOXT) atomicAdd(&acc[r1], w.y * r);
        if (r2 < VOXT) atomicAdd(&acc[r2], w.z * r);
        if (r3 < VOXT) atomicAdd(&acc[r3], w.w * r);
    }
    __syncthreads();

    float4* dst = (float4*)(part + ((size_t)c * 4 + b) * NVOX + lo);
    const float4* src = (const float4*)acc;
    for (int q = threadIdx.x; q < VOXT / 4; q += 1024) dst[q] = src[q];
}

// conv1: 1->16ch 3x3 SAME + bias + relu. Input from xt (NVOX,4), output h (B,NVOX,16).
__global__ __launch_bounds__(256) void k_conv1(
    const float* __restrict__ xt,
    const float* __restrict__ w1,  // (16,1,3,3)
    const float* __restrict__ b1,  // (16)
    float* __restrict__ h)         // (B, NVOX, 16)
{
    int t = blockIdx.x * blockDim.x + threadIdx.x;  // over B*NVOX
    int b = t >> 16;
    int v = t & 65535;
    int i = v >> 8, j = v & 255;
    float in[3][3];
#pragma unroll
    for (int di = 0; di < 3; ++di)
#pragma unroll
        for (int dj = 0; dj < 3; ++dj) {
            int ii = i + di - 1, jj = j + dj - 1;
            in[di][dj] = (ii >= 0 && ii < N0 && jj >= 0 && jj < N1)
                             ? xt[(size_t)((ii << 8) | jj) * 4 + b]
                             : 0.0f;
        }
    float* hp = h + (size_t)t * CH;
#pragma unroll
    for (int c = 0; c < CH; ++c) {
        float acc = b1[c];
#pragma unroll
        for (int di = 0; di < 3; ++di)
#pragma unroll
            for (int dj = 0; dj < 3; ++dj)
                acc += in[di][dj] * w1[c * 9 + di * 3 + dj];
        hp[c] = fmaxf(acc, 0.0f);
    }
}

// conv2 (16->1 3x3 SAME) fused with the MLEM combine; sums the C chunk partials.
__global__ __launch_bounds__(256) void k_combine(
    const float* __restrict__ h,      // (B,NVOX,16)
    const float* __restrict__ w2,     // (1,16,3,3)
    const float* __restrict__ b2,     // (1)
    const float* __restrict__ part,   // (C,4,NVOX)
    const float* __restrict__ xt_in,  // (NVOX,4)
    const float* __restrict__ osem,   // (B,NVOX)
    const float* __restrict__ adj,    // adjoint_ones + s*NVOX ; index b*NSUB*NVOX+v
    const float* __restrict__ nwp,    // scalar
    int C,
    float* __restrict__ xt_out,       // (NVOX,4)
    float* __restrict__ out_planar)   // (B,NVOX) or nullptr
{
    int t = blockIdx.x * blockDim.x + threadIdx.x;  // over B*NVOX
    int b = t >> 16;
    int v = t & 65535;
    int i = v >> 8, j = v & 255;

    float o = b2[0];
#pragma unroll
    for (int di = 0; di < 3; ++di) {
        int ii = i + di - 1;
        if (ii < 0 || ii >= N0) continue;
#pragma unroll
        for (int dj = 0; dj < 3; ++dj) {
            int jj = j + dj - 1;
            if (jj < 0 || jj >= N1) continue;
            const float* hp = h + ((size_t)b * NVOX + ((ii << 8) | jj)) * CH;
#pragma unroll
            for (int c = 0; c < CH; ++c)
                o += hp[c] * w2[c * 9 + di * 3 + dj];
        }
    }
    // sum the per-chunk partial backprojections (coalesced: consecutive v)
    float bk = 0.0f;
    for (int c = 0; c < C; ++c)
        bk += part[((size_t)c * 4 + b) * NVOX + v];

    float xv = xt_in[(size_t)v * 4 + b];
    float x_data = bk * xv / adj[(size_t)b * NSUB * NVOX + v];
    float xnew = osem[t] - x_data + nwp[0] * o;
    xnew = fmaxf(xnew, 0.0f);
    xt_out[(size_t)v * 4 + b] = xnew;
    if (out_planar) out_planar[t] = xnew;
}

extern "C" void kernel_launch(void* const* d_in, const int* in_sizes, int n_in,
                              void* d_out, int out_size, void* d_ws, size_t ws_size,
                              hipStream_t stream) {
    const float* osem   = (const float*)d_in[0];
    const float* data   = (const float*)d_in[1];
    const float* mult   = (const float*)d_in[2];
    const float* contam = (const float*)d_in[3];
    const float* adj    = (const float*)d_in[4];
    const float* norm   = (const float*)d_in[5];
    const int*   ray_idx = (const int*)d_in[6];
    const float* pw     = (const float*)d_in[7];
    const float* w1     = (const float*)d_in[8];
    const float* b1     = (const float*)d_in[9];
    const float* w2     = (const float*)d_in[10];
    const float* b2     = (const float*)d_in[11];
    const float* nw     = (const float*)d_in[12];
    float* out = (float*)d_out;

    // choose chunk count C from available workspace:
    // layout: xtA (1MB) | xtB (1MB) | part (C MB) | h (16MB, ratio aliases h[0:512KB])
    const size_t MB = 1024 * 1024;
    int C = (ws_size >= (18 + 32) * MB + NVOX) ? 32
          : (ws_size >= (18 + 16) * MB + NVOX) ? 16 : 8;
    const int PC = NPTS / C;  // multiple of 4096 for C in {8,16,32}

    float* ws   = (float*)d_ws;
    float* xtA  = ws;
    float* xtB  = ws + (size_t)NVOX * 4;
    float* part = ws + (size_t)NVOX * 8;
    float* h    = part + (size_t)C * NVOX * 4;
    float* ratio = h;  // dead before k_conv1 writes h

    k_transpose<<<NVOX / 256, 256, 0, stream>>>(osem, xtA);

    const int subsets[4] = {0, 2, 4, 6};
    float* xin = xtA;
    float* xout = xtB;
    for (int it = 0; it < 4; ++it) {
        int s = subsets[it];
        const int*   rs = ray_idx + (size_t)s * NPTS;
        const float* ps = pw + (size_t)s * NPTS;
        k_fwd<<<NLOR / 4, 256, 0, stream>>>(
            rs, ps, xin,
            data + (size_t)s * NLOR,
            mult + (size_t)s * NLOR,
            contam + (size_t)s * NLOR,
            norm, ratio);
        k_back<<<dim3(C, 8), 1024, 0, stream>>>(rs, ps, ratio, part, PC);
        k_conv1<<<(BB * NVOX) / 256, 256, 0, stream>>>(xin, w1, b1, h);
        k_combine<<<(BB * NVOX) / 256, 256, 0, stream>>>(
            h, w2, b2, part, xin, osem,
            adj + (size_t)s * NVOX, nw, C,
            xout, (it == 3) ? out : nullptr);
        float* tmp = xin; xin = xout; xout = tmp;
    }
}